// Round 1
// baseline (785.732 us; speedup 1.0000x reference)
//
#include <hip/hip_runtime.h>
#include <math.h>

constexpr int B   = 4;
constexpr int N   = 2304;
constexpr int DIM = 256;
constexpr int NH  = 8;
constexpr int DH  = 32;
constexpr int M   = B * N;        // 9216 rows
constexpr int SPLIT  = 2;
constexpr int KCHUNK = N / SPLIT; // 1152

// ---------------- LayerNorm: one block (256 thr) per row ----------------
__global__ __launch_bounds__(256) void ln_kernel(
    const float* __restrict__ x, const float* __restrict__ g,
    const float* __restrict__ bta, float* __restrict__ xn)
{
    __shared__ float red[4];
    int row = blockIdx.x;
    int t   = threadIdx.x;
    float v = x[(size_t)row * DIM + t];
    float s = v;
    #pragma unroll
    for (int o = 32; o > 0; o >>= 1) s += __shfl_down(s, o, 64);
    if ((t & 63) == 0) red[t >> 6] = s;
    __syncthreads();
    float mu = (red[0] + red[1] + red[2] + red[3]) * (1.0f / DIM);
    __syncthreads();
    float d  = v - mu;
    float s2 = d * d;
    #pragma unroll
    for (int o = 32; o > 0; o >>= 1) s2 += __shfl_down(s2, o, 64);
    if ((t & 63) == 0) red[t >> 6] = s2;
    __syncthreads();
    float var = (red[0] + red[1] + red[2] + red[3]) * (1.0f / DIM);
    float r   = rsqrtf(var + 1e-5f);
    xn[(size_t)row * DIM + t] = d * r * g[t] + bta[t];
}

// ---------------- fp32 SGEMM: C(M x 256) = A(M x 256) @ W(256 x 256) + bias
// LAYOUT 0: plain row-major out[r*256+c]
// LAYOUT 1: QKV scatter out[((b*8+h)*N+n)*32+d]
template<int LAYOUT>
__global__ __launch_bounds__(256) void gemm_kernel(
    const float* __restrict__ A, const float* __restrict__ W,
    const float* __restrict__ bias, float* __restrict__ out)
{
    __shared__ float As[64][33];   // +1 pad: kills row-stride bank conflicts
    __shared__ float Bs[32][64];
    int tid = threadIdx.x;
    int tx = tid & 15, ty = tid >> 4;
    int row0 = blockIdx.y * 64;
    int col0 = blockIdx.x * 64;
    float acc[4][4] = {};
    for (int kk = 0; kk < DIM; kk += 32) {
        #pragma unroll
        for (int f = tid; f < 512; f += 256) {      // A tile 64x32
            int r = f >> 3, c4 = (f & 7) << 2;
            const float4 a = *(const float4*)&A[(size_t)(row0 + r) * DIM + kk + c4];
            As[r][c4 + 0] = a.x; As[r][c4 + 1] = a.y;
            As[r][c4 + 2] = a.z; As[r][c4 + 3] = a.w;
        }
        #pragma unroll
        for (int f = tid; f < 512; f += 256) {      // B tile 32x64
            int r = f >> 4, c4 = (f & 15) << 2;
            *(float4*)&Bs[r][c4] = *(const float4*)&W[(size_t)(kk + r) * DIM + col0 + c4];
        }
        __syncthreads();
        #pragma unroll
        for (int k = 0; k < 32; ++k) {
            float a0 = As[ty*4+0][k], a1 = As[ty*4+1][k];
            float a2 = As[ty*4+2][k], a3 = As[ty*4+3][k];
            float4 b4 = *(float4*)&Bs[k][tx*4];
            acc[0][0] += a0*b4.x; acc[0][1] += a0*b4.y; acc[0][2] += a0*b4.z; acc[0][3] += a0*b4.w;
            acc[1][0] += a1*b4.x; acc[1][1] += a1*b4.y; acc[1][2] += a1*b4.z; acc[1][3] += a1*b4.w;
            acc[2][0] += a2*b4.x; acc[2][1] += a2*b4.y; acc[2][2] += a2*b4.z; acc[2][3] += a2*b4.w;
            acc[3][0] += a3*b4.x; acc[3][1] += a3*b4.y; acc[3][2] += a3*b4.z; acc[3][3] += a3*b4.w;
        }
        __syncthreads();
    }
    int c0 = col0 + tx * 4;
    float4 bv = *(const float4*)&bias[c0];
    #pragma unroll
    for (int i = 0; i < 4; ++i) {
        int r = row0 + ty * 4 + i;
        float4 o;
        o.x = acc[i][0] + bv.x; o.y = acc[i][1] + bv.y;
        o.z = acc[i][2] + bv.z; o.w = acc[i][3] + bv.w;
        if (LAYOUT == 0) {
            *(float4*)&out[(size_t)r * DIM + c0] = o;
        } else {
            int b = r / N, n = r - b * N;
            int h = c0 >> 5, d = c0 & 31;
            *(float4*)&out[(((size_t)(b * NH + h)) * N + n) * DH + d] = o;
        }
    }
}

// ---------------- Attention: 1 query/thread, 64-key LDS tiles, key-split ----
// Multiplicative column mask BEFORE softmax (exp(0)=1 for masked cols), no
// max-subtraction (scores bounded |s|<~3) so key-split partials are additive.
__global__ __launch_bounds__(64) void attn_kernel(
    const float* __restrict__ q, const float* __restrict__ k,
    const float* __restrict__ v, const float* __restrict__ mask,
    float* __restrict__ po, float* __restrict__ pl)
{
    __shared__ float ks[64 * DH];
    __shared__ float vs[64 * DH];
    __shared__ float ms[64];
    int bh = blockIdx.y;           // b*8+h
    int sp = blockIdx.z;
    int b  = bh >> 3;
    int qi = blockIdx.x * 64 + threadIdx.x;
    const float* qb = q + ((size_t)bh * N + qi) * DH;
    float qr[DH];
    #pragma unroll
    for (int i = 0; i < DH / 4; ++i) {
        float4 t = *(const float4*)&qb[i * 4];
        qr[i*4+0] = t.x; qr[i*4+1] = t.y; qr[i*4+2] = t.z; qr[i*4+3] = t.w;
    }
    float o[DH] = {};
    float l = 0.f;
    int j0base = sp * KCHUNK;
    for (int j0 = j0base; j0 < j0base + KCHUNK; j0 += 64) {
        __syncthreads();
        const float* kb = k + ((size_t)bh * N + j0) * DH;
        const float* vb = v + ((size_t)bh * N + j0) * DH;
        #pragma unroll
        for (int f = threadIdx.x; f < 512; f += 64) {
            *(float4*)&ks[f * 4] = *(const float4*)&kb[f * 4];
            *(float4*)&vs[f * 4] = *(const float4*)&vb[f * 4];
        }
        ms[threadIdx.x] = mask[(size_t)b * N + j0 + threadIdx.x] > 0.f ? 1.f : 0.f;
        __syncthreads();
        for (int j = 0; j < 64; ++j) {
            const float* kj = &ks[j * DH];
            float s0 = 0.f, s1 = 0.f, s2 = 0.f, s3 = 0.f;
            #pragma unroll
            for (int d = 0; d < DH; d += 4) {
                s0 += qr[d+0] * kj[d+0];
                s1 += qr[d+1] * kj[d+1];
                s2 += qr[d+2] * kj[d+2];
                s3 += qr[d+3] * kj[d+3];
            }
            float s = (s0 + s1) + (s2 + s3);
            float p = __expf(s * ms[j]);
            l += p;
            const float* vj = &vs[j * DH];
            #pragma unroll
            for (int d = 0; d < DH; ++d) o[d] += p * vj[d];
        }
    }
    size_t pidx = (size_t)(bh * SPLIT + sp) * N + qi;
    pl[pidx] = l;
    float* pob = po + pidx * DH;
    #pragma unroll
    for (int i = 0; i < DH / 4; ++i) {
        float4 t;
        t.x = o[i*4+0]; t.y = o[i*4+1]; t.z = o[i*4+2]; t.w = o[i*4+3];
        *(float4*)&pob[i * 4] = t;
    }
}

// ---------------- Combine key-split partials, write (B,N,DIM) layout --------
__global__ __launch_bounds__(256) void combine_kernel(
    const float* __restrict__ po, const float* __restrict__ pl,
    float* __restrict__ attn_out)
{
    int idx = blockIdx.x * blockDim.x + threadIdx.x;  // one (bh, qi) per thread
    if (idx >= B * NH * N) return;
    int bh = idx / N;
    int qi = idx - bh * N;
    int b = bh >> 3, h = bh & 7;
    float l = 0.f;
    #pragma unroll
    for (int sp = 0; sp < SPLIT; ++sp) l += pl[(size_t)(bh * SPLIT + sp) * N + qi];
    float inv = 1.f / l;
    float* ob = attn_out + ((size_t)(b * N + qi)) * DIM + h * DH;
    #pragma unroll
    for (int i = 0; i < DH / 4; ++i) {
        float4 acc = {0.f, 0.f, 0.f, 0.f};
        #pragma unroll
        for (int sp = 0; sp < SPLIT; ++sp) {
            const float4 t = *(const float4*)&po[((size_t)(bh * SPLIT + sp) * N + qi) * DH + i * 4];
            acc.x += t.x; acc.y += t.y; acc.z += t.z; acc.w += t.w;
        }
        acc.x *= inv; acc.y *= inv; acc.z *= inv; acc.w *= inv;
        *(float4*)&ob[i * 4] = acc;
    }
}

extern "C" void kernel_launch(void* const* d_in, const int* in_sizes, int n_in,
                              void* d_out, int out_size, void* d_ws, size_t ws_size,
                              hipStream_t stream)
{
    const float* x    = (const float*)d_in[0];
    const float* mask = (const float*)d_in[1];
    const float* ln_g = (const float*)d_in[2];
    const float* ln_b = (const float*)d_in[3];
    const float* Wq   = (const float*)d_in[4];
    const float* bq   = (const float*)d_in[5];
    const float* Wk   = (const float*)d_in[6];
    const float* bk   = (const float*)d_in[7];
    const float* Wv   = (const float*)d_in[8];
    const float* bv   = (const float*)d_in[9];
    const float* Wp   = (const float*)d_in[10];
    const float* bp   = (const float*)d_in[11];
    float* out = (float*)d_out;

    float* ws = (float*)d_ws;
    constexpr size_t SZ = (size_t)M * DIM;   // 2359296 floats
    float* xn = ws;
    float* qb_ = ws + SZ;
    float* kb_ = ws + 2 * SZ;
    float* vb_ = ws + 3 * SZ;
    float* po  = ws + 4 * SZ;                              // 32*2*2304*32 floats
    float* pl  = po + (size_t)B * NH * SPLIT * N * DH;     // 32*2*2304 floats
    float* attn = xn;  // xn dead after the 3 QKV GEMMs; reuse for attention out

    ln_kernel<<<M, 256, 0, stream>>>(x, ln_g, ln_b, xn);

    dim3 ggrid(DIM / 64, M / 64);  // (4, 144)
    gemm_kernel<1><<<ggrid, 256, 0, stream>>>(xn, Wq, bq, qb_);
    gemm_kernel<1><<<ggrid, 256, 0, stream>>>(xn, Wk, bk, kb_);
    gemm_kernel<1><<<ggrid, 256, 0, stream>>>(xn, Wv, bv, vb_);

    dim3 agrid(N / 64, B * NH, SPLIT);  // (36, 32, 2)
    attn_kernel<<<agrid, 64, 0, stream>>>(qb_, kb_, vb_, mask, po, pl);

    combine_kernel<<<(B * NH * N) / 256, 256, 0, stream>>>(po, pl, attn);

    gemm_kernel<0><<<ggrid, 256, 0, stream>>>(attn, Wp, bp, out);
}